// Round 6
// baseline (1154.302 us; speedup 1.0000x reference)
//
#include <hip/hip_runtime.h>
#include <math.h>

using half8 = __attribute__((ext_vector_type(8))) _Float16;
using half4 = __attribute__((ext_vector_type(4))) _Float16;
using f32x4 = __attribute__((ext_vector_type(4))) float;

// ---------------------------------------------------------------------------
// Weight re-tiling: w (OIHW fp32) -> Wt fp16 tiles [mt][ktile][g][mi][8].
// ktile order: cc (ci chunks of 128) -> khkw (9) -> sub (cw/32).
// Element (g,mi,i) of tile = w[mt*BM+mi][cc*128+sub*32+8g+i][khkw].
// ---------------------------------------------------------------------------
template<int CIN, int KC, int M_, int BM>
__global__ __launch_bounds__(256)
void transform_w(const float* __restrict__ w, _Float16* __restrict__ wt) {
  constexpr int NT = (KC / 32) * 9;
  __shared__ float lds[32 * 289];
  const int tid = threadIdx.x;
  const int s   = blockIdx.x;          // ci chunk of 32: ci0 = 32*s
  const int m0  = blockIdx.y * 32;
  const int ci0 = s * 32;
  int vlen = (CIN - ci0) * 9;          // valid floats per row chunk
  if (vlen > 288) vlen = 288;
  if (vlen < 0) vlen = 0;

  for (int e = tid; e < 32 * 288; e += 256) {
    const int mi = e / 288, o = e - mi * 288;
    float v = 0.f;
    if (o < vlen) v = w[(size_t)(m0 + mi) * (CIN * 9) + (size_t)ci0 * 9 + o];
    lds[mi * 289 + o] = v;
  }
  __syncthreads();

  const int cc  = s >> 2;
  const int sub = s & 3;
  int ns = (KC - 128 * cc) / 32; if (ns > 4) ns = 4;
  const int mt = m0 / BM;
  const int mb = m0 - mt * BM;
  _Float16* base = wt + (size_t)mt * NT * (BM * 32);

  for (int u = tid; u < 36 * 256; u += 256) {
    const int chunk  = u >> 8;
    const int within = u & 255;
    const int g = chunk & 3, khkw = chunk >> 2;
    const int mi = within >> 3, i = within & 7;
    const int kt = 36 * cc + khkw * ns + sub;
    const float v = lds[mi * 289 + (8 * g + i) * 9 + khkw];
    base[(size_t)kt * (BM * 32) + g * (BM * 8) + (mb + mi) * 8 + i] = (_Float16)v;
  }
}

// ---------------------------------------------------------------------------
// Convert + transpose roi: (256, 2048, 49) fp32 NCHW -> xh1[obj][pos][ci] fp16.
// Block = (128-ci chunk, obj). LDS-staged so reads and writes are coalesced.
// ---------------------------------------------------------------------------
__global__ __launch_bounds__(256)
void convert_tr(const float* __restrict__ x, _Float16* __restrict__ xh) {
  __shared__ _Float16 t_s[49][136];
  const int tid   = threadIdx.x;
  const int cbase = blockIdx.x * 128;
  const int obj   = blockIdx.y;
  const float* src = x + (size_t)obj * 2048 * 49 + (size_t)cbase * 49;
  for (int e = tid; e < 128 * 49; e += 256) {
    const int ci = e / 49, pos = e - ci * 49;
    t_s[pos][ci] = (_Float16)src[e];
  }
  __syncthreads();
  _Float16* dst = xh + (size_t)obj * 49 * 2048 + cbase;
  for (int u = tid; u < 49 * 16; u += 256) {
    const int pos = u >> 4, l = u & 15;
    *(half8*)&dst[(size_t)pos * 2048 + l * 8] = *(const half8*)&t_s[pos][l * 8];
  }
}

// ---------------------------------------------------------------------------
// fp16 MFMA implicit-GEMM conv for 3x3 convs on 7x7 inputs.
// TIN=true: X is fp16 transposed [obj][pos][XROW] -> staging = half8 coalesced
//   loads + conflict-free ds_write_b128, async-split (chunk c+1 loads issued
//   before the barrier, hidden under chunk c's MFMAs).
// TIN=false: X is fp32 NCHW, per-element staging (fallback).
// TOUT=true: output written fp16 transposed [obj][pos][outc] at co_off.
// Weights double-buffered in registers from global (linear walk).
// ---------------------------------------------------------------------------
template<int KC, int M_, int BM, int FN, int OHW, int PAD, bool TIN, int XROW,
         bool TOUT, typename OUT_T, typename IN_T>
__global__ __launch_bounds__(512, 4)
void conv_mfma(const _Float16* __restrict__ Wt, const IN_T* __restrict__ X,
               const float* __restrict__ bias, OUT_T* __restrict__ out,
               int outc, int co_off) {
  constexpr int NT   = (KC / 32) * 9;
  constexpr int OPOS = OHW * OHW;
  constexpr int WM   = BM / 4;
  constexpr int FR   = WM / 16;

  __shared__ alignas(16) _Float16 x_s[2][50][136];

  const int tid  = threadIdx.x;
  const int wid  = tid >> 6;
  const int lane = tid & 63;
  const int g    = lane >> 4;
  const int ln   = lane & 15;
  const int obj  = wid >> 2;
  const int wm   = (wid & 3) * WM;
  const int mt   = blockIdx.x;
  const int op   = blockIdx.y;

  if (tid < 272) x_s[tid / 136][49][tid % 136] = (_Float16)0.f;

  int ohv[FN], owv[FN];
  bool pvv[FN];
#pragma unroll
  for (int f = 0; f < FN; f++) {
    const int pos = ln + 16 * f;
    pvv[f] = pos < OPOS;
    ohv[f] = pos / OHW;
    owv[f] = pos % OHW;
  }

  f32x4 acc[FR][FN];
#pragma unroll
  for (int r = 0; r < FR; r++)
#pragma unroll
    for (int f = 0; f < FN; f++) acc[r][f] = (f32x4){0.f, 0.f, 0.f, 0.f};

  const _Float16* Xh = nullptr;
  if constexpr (TIN) Xh = (const _Float16*)X + (size_t)(2 * op) * 49 * XROW;

  half8 rg[4];
  auto load_chunk = [&](int cbase, int cw) {
    if (cw == 128) {
#pragma unroll
      for (int v = 0; v < 4; v++) {
        const int u = v * 512 + tid;
        if (u < 1568) {
          const int row = u >> 4, l = u & 15;
          const int o = row >= 49 ? 1 : 0, pos = row - 49 * o;
          rg[v] = *(const half8*)(Xh + (size_t)(o * 49 + pos) * XROW + cbase + l * 8);
        }
      }
    } else {  // cw == 32
      if (tid < 392) {
        const int row = tid >> 2, l = tid & 3;
        const int o = row >= 49 ? 1 : 0, pos = row - 49 * o;
        rg[0] = *(const half8*)(Xh + (size_t)(o * 49 + pos) * XROW + cbase + l * 8);
      }
    }
  };
  auto write_chunk = [&](int cw) {
    if (cw == 128) {
#pragma unroll
      for (int v = 0; v < 4; v++) {
        const int u = v * 512 + tid;
        if (u < 1568) {
          const int row = u >> 4, l = u & 15;
          const int o = row >= 49 ? 1 : 0, pos = row - 49 * o;
          *(half8*)&x_s[o][pos][l * 8] = rg[v];
        }
      }
    } else {
      if (tid < 392) {
        const int row = tid >> 2, l = tid & 3;
        const int o = row >= 49 ? 1 : 0, pos = row - 49 * o;
        *(half8*)&x_s[o][pos][l * 8] = rg[0];
      }
    }
  };

  // weight register double-buffer (afn = next ktile; final prefetch lands
  // 16KB past this mt tile -- valid ws memory, values unused)
  const _Float16* ap = Wt + (size_t)mt * NT * (BM * 32) + (g * BM + wm + ln) * 8;
  half8 afn[FR];
#pragma unroll
  for (int r = 0; r < FR; r++) afn[r] = *(const half8*)(ap + r * 128);

  if constexpr (TIN) load_chunk(0, KC < 128 ? KC : 128);

  for (int cbase = 0; cbase < KC; cbase += 128) {
    const int cw = (KC - cbase < 128) ? (KC - cbase) : 128;
    __syncthreads();   // all waves done reading previous x_s chunk
    if constexpr (TIN) {
      write_chunk(cw);
      if (cbase + 128 < KC) {
        const int nw = (KC - cbase - 128 < 128) ? (KC - cbase - 128) : 128;
        load_chunk(cbase + 128, nw);   // in flight across the next MFMA phase
      }
    } else {
      for (int e = tid; e < 2 * cw * 49; e += 512) {
        const int o = e / (cw * 49);
        const int r = e - o * (cw * 49);
        const int ci = r / 49, pos = r - ci * 49;
        const float v = (float)(X[(size_t)(2 * op + o) * KC * 49 + (size_t)cbase * 49 + r]);
        x_s[o][pos][ci] = (_Float16)v;
      }
    }
    __syncthreads();
    const int nsub = cw / 32;
    for (int khkw = 0; khkw < 9; khkw++) {
      const int kh = khkw / 3, kw = khkw - 3 * (khkw / 3);
      int boff[FN];
#pragma unroll
      for (int f = 0; f < FN; f++) {
        const int ih = ohv[f] + kh - PAD;
        const int iw = owv[f] + kw - PAD;
        bool v = pvv[f];
        if (PAD) v = v && ((unsigned)ih < 7u) && ((unsigned)iw < 7u);
        const int row = v ? (ih * 7 + iw) : 49;
        boff[f] = (obj * 50 * 136 + row * 136) * 2;
      }
      for (int sub = 0; sub < nsub; sub++) {
        half8 af[FR];
#pragma unroll
        for (int r = 0; r < FR; r++) af[r] = afn[r];
        ap += BM * 32;
#pragma unroll
        for (int r = 0; r < FR; r++)
          afn[r] = *(const half8*)(ap + r * 128);
        const char* xb = (const char*)(&x_s[0][0][0]) + (sub * 32 + 8 * g) * 2;
#pragma unroll
        for (int f = 0; f < FN; f++) {
          const half8 bf = *(const half8*)(xb + boff[f]);
#pragma unroll
          for (int r = 0; r < FR; r++)
            acc[r][f] = __builtin_amdgcn_mfma_f32_16x16x32_f16(af[r], bf, acc[r][f], 0, 0, 0);
        }
      }
    }
  }

  // epilogue: D layout col=lane&15 (n=pos), row=(lane>>4)*4+e
  const int bo = 2 * op + obj;
#pragma unroll
  for (int f = 0; f < FN; f++) {
    const int pos = ln + 16 * f;
    if (pos < OPOS) {
#pragma unroll
      for (int r = 0; r < FR; r++) {
        const int mrow = mt * BM + wm + r * 16 + g * 4;
        if constexpr (TOUT) {
          half4 h;
#pragma unroll
          for (int e = 0; e < 4; e++)
            h[e] = (_Float16)fmaxf(acc[r][f][e] + bias[mrow + e], 0.f);
          *(half4*)&((_Float16*)out)[((size_t)bo * OPOS + pos) * outc + co_off + mrow] = h;
        } else {
#pragma unroll
          for (int e = 0; e < 4; e++) {
            const int m = mrow + e;
            float v = fmaxf(acc[r][f][e] + bias[m], 0.f);
            out[((size_t)bo * outc + co_off + m) * OPOS + pos] = (OUT_T)v;
          }
        }
      }
    }
  }
}

// ---------------------------------------------------------------------------
// fp32 implicit-GEMM conv + optional split-K partial output (glob path).
// ---------------------------------------------------------------------------
template<int M_, int CIN, int KH, int KW, int H, int W, int OH, int OW,
         int STRIDE, int PAD, int BATCH, int OUTC, int CO_OFF, bool RELU,
         int TM, int TN, int KSPLIT, bool PARTIAL>
__global__ __launch_bounds__(256)
void conv_gemm(const float* __restrict__ A,
               const float* __restrict__ X,
               const float* __restrict__ bias,
               float* __restrict__ out) {
  constexpr int K   = CIN * KH * KW;
  constexpr int N   = BATCH * OH * OW;
  constexpr int BK  = 16;
  constexpr int BM  = 16 * TM;
  constexpr int BN  = 16 * TN;
  constexpr int KCH = K / KSPLIT;

  __shared__ float a_s[BK][BM];
  __shared__ float b_s[BK][BN];

  const int t  = threadIdx.x;
  const int tx = t & 15;
  const int ty = t >> 4;
  const int n0 = blockIdx.x * BN;
  const int m0 = blockIdx.y * BM;
  const int kz = blockIdx.z;

  constexpr int AQ    = TM / 4;
  constexpr int TPR_A = 4 / AQ;
  const int am = t / TPR_A;
  const int ak = (t % TPR_A) * (4 * AQ);

  constexpr int BQ = TN / 4;
  const int bk = t & 15;
  const int bn = (t >> 4) * TN;

  float acc[TM][TN];
#pragma unroll
  for (int i = 0; i < TM; i++)
#pragma unroll
    for (int j = 0; j < TN; j++) acc[i][j] = 0.f;

  for (int k0 = kz * KCH; k0 < (kz + 1) * KCH; k0 += BK) {
    float4 av[AQ];
#pragma unroll
    for (int q = 0; q < AQ; q++) {
      av[q] = make_float4(0.f, 0.f, 0.f, 0.f);
      const int kq = k0 + ak + 4 * q;
      if ((m0 + am) < M_ && kq < K)
        av[q] = *reinterpret_cast<const float4*>(&A[(m0 + am) * K + kq]);
    }
    float bv[TN];
#pragma unroll
    for (int q = 0; q < TN; q++) bv[q] = 0.f;
    {
      const int kk = k0 + bk;
      if (kk < K) {
        const int ci = kk / (KH * KW);
        const int r  = kk - ci * (KH * KW);
        const int kh = r / KW;
        const int kw = r - kh * KW;
#pragma unroll
        for (int q = 0; q < TN; q++) {
          const int n = n0 + bn + q;
          if (n < N) {
            const int b   = n / (OH * OW);
            const int pos = n - b * (OH * OW);
            const int oh  = pos / OW;
            const int ow  = pos - oh * OW;
            const int ih  = oh * STRIDE - PAD + kh;
            const int iw  = ow * STRIDE - PAD + kw;
            if (ih >= 0 && ih < H && iw >= 0 && iw < W)
              bv[q] = X[((b * CIN + ci) * H + ih) * W + iw];
          }
        }
      }
    }
    __syncthreads();
#pragma unroll
    for (int q = 0; q < AQ; q++) {
      const int kq = ak + 4 * q;
      a_s[kq + 0][am] = av[q].x;
      a_s[kq + 1][am] = av[q].y;
      a_s[kq + 2][am] = av[q].z;
      a_s[kq + 3][am] = av[q].w;
    }
#pragma unroll
    for (int q = 0; q < BQ; q++)
      *reinterpret_cast<float4*>(&b_s[bk][bn + 4 * q]) =
          make_float4(bv[4 * q], bv[4 * q + 1], bv[4 * q + 2], bv[4 * q + 3]);
    __syncthreads();
#pragma unroll
    for (int kk2 = 0; kk2 < BK; kk2++) {
      float a[TM], b[TN];
#pragma unroll
      for (int q = 0; q < AQ; q++)
        *reinterpret_cast<float4*>(&a[4 * q]) =
            *reinterpret_cast<const float4*>(&a_s[kk2][ty * TM + 4 * q]);
#pragma unroll
      for (int q = 0; q < BQ; q++)
        *reinterpret_cast<float4*>(&b[4 * q]) =
            *reinterpret_cast<const float4*>(&b_s[kk2][tx * TN + 4 * q]);
#pragma unroll
      for (int i = 0; i < TM; i++)
#pragma unroll
        for (int j = 0; j < TN; j++)
          acc[i][j] = fmaf(a[i], b[j], acc[i][j]);
    }
  }

#pragma unroll
  for (int i = 0; i < TM; i++) {
    const int m = m0 + ty * TM + i;
    if (m < M_) {
#pragma unroll
      for (int j = 0; j < TN; j++) {
        const int n = n0 + tx * TN + j;
        if (n < N) {
          if (PARTIAL) {
            out[((size_t)kz * M_ + m) * N + n] = acc[i][j];
          } else {
            float v = acc[i][j] + bias[m];
            if (RELU) v = fmaxf(v, 0.f);
            const int b   = n / (OH * OW);
            const int pos = n - b * (OH * OW);
            out[(b * OUTC + CO_OFF + m) * (OH * OW) + pos] = v;
          }
        }
      }
    }
  }
}

__global__ void reduce_bias_relu(const float* __restrict__ part,
                                 const float* __restrict__ bias,
                                 float* __restrict__ out, int MN, int N, int KS) {
  const int e = blockIdx.x * 256 + threadIdx.x;
  if (e >= MN) return;
  float s = 0.f;
  for (int k = 0; k < KS; k++) s += part[(size_t)k * MN + e];
  s += bias[e / N];
  out[e] = fmaxf(s, 0.f);
}

// ---------------------------------------------------------------------------
// sel2: x = sel1buf f32 (256,256,5,5) NCHW, w (16,256,3,3) -> out (256,16,9).
// ---------------------------------------------------------------------------
__global__ __launch_bounds__(256)
void sel2_kernel(const float* __restrict__ x, const float* __restrict__ w,
                 const float* __restrict__ b, float* __restrict__ out) {
  const int wv   = (blockIdx.x * 256 + threadIdx.x) >> 6;
  const int lane = threadIdx.x & 63;
  const int obj  = wv >> 4, co = wv & 15;
  float acc[9];
#pragma unroll
  for (int p = 0; p < 9; p++) acc[p] = 0.f;
  const float* xo = x + (size_t)obj * 256 * 25;
  const float* wo = w + (size_t)co * 2304;
  for (int k = lane; k < 2304; k += 64) {
    const int ci = k / 9, rr = k - 9 * ci;
    const int kh = rr / 3, kw = rr - 3 * kh;
    const float wval = wo[k];
    const float* xc = xo + ci * 25;
#pragma unroll
    for (int oh = 0; oh < 3; oh++)
#pragma unroll
      for (int ow = 0; ow < 3; ow++)
        acc[oh * 3 + ow] = fmaf(xc[(oh + kh) * 5 + (ow + kw)], wval, acc[oh * 3 + ow]);
  }
  const float bv = b[co];
#pragma unroll
  for (int p = 0; p < 9; p++) {
    float v = acc[p];
#pragma unroll
    for (int off = 32; off; off >>= 1) v += __shfl_xor(v, off);
    if (lane == 0) out[(size_t)wv * 9 + p] = fmaxf(v + bv, 0.f);
  }
}

// ---------------------------------------------------------------------------
// sin_t buffer (256, 49, 544) fp16: ch 0..3 = bb, 260..515 = glob, 516..543=0.
// (ch 4..259 written by obj2 conv's TOUT epilogue.)
// ---------------------------------------------------------------------------
__global__ void prep_sin_t(const float* __restrict__ bbox,
                           const float* __restrict__ glob,
                           _Float16* __restrict__ sint) {
  const int b = blockIdx.x;
  const float x0 = bbox[b * 4 + 0], y0 = bbox[b * 4 + 1];
  const float x1 = bbox[b * 4 + 2], y1 = bbox[b * 4 + 3];
  const float bbv[4] = {x0 / 1280.f, y0 / 720.f,
                        logf(1280.f / (x1 - x0)), logf(720.f / (y1 - y0))};
  _Float16* base = sint + (size_t)b * 49 * 544;
  for (int e = threadIdx.x; e < 49 * 288; e += blockDim.x) {
    const int pos = e / 288, q = e - pos * 288;
    float v; int c;
    if (q < 4)        { v = bbv[q];                  c = q; }
    else if (q < 260) { v = glob[(q - 4) * 49 + pos]; c = q + 256; }
    else              { v = 0.f;                      c = q + 256; }
    base[pos * 544 + c] = (_Float16)v;
  }
}

__global__ void score_top5(const float* __restrict__ sel2,
                           const float* __restrict__ w3,
                           const float* __restrict__ b3,
                           int* __restrict__ idx_out) {
  __shared__ float w_s[144];
  __shared__ float s_s[256];
  const int t = threadIdx.x;
  if (t < 144) w_s[t] = w3[t];
  __syncthreads();
  float acc = b3[0];
  const float* p = sel2 + t * 144;
  for (int k = 0; k < 144; k++) acc += p[k] * w_s[k];
  s_s[t] = acc;
  __syncthreads();
  if (t == 0) {
    for (int i = 0; i < 5; i++) {
      float best = -1e30f;
      int bi = 0;
      for (int j = 0; j < 256; j++)
        if (s_s[j] > best) { best = s_s[j]; bi = j; }
      idx_out[i] = bi;
      s_s[bi] = -1e30f;
    }
  }
}

// pool over sin_t transposed layout
__global__ void pool_t(const _Float16* __restrict__ sint,
                       const float* __restrict__ glob,
                       const int* __restrict__ idx,
                       float* __restrict__ objsel,
                       float* __restrict__ g) {
  const int blk = blockIdx.x;
  const int t = threadIdx.x;
  if (blk < 5) {
    const int b = idx[blk];
    const _Float16* base = sint + (size_t)b * 49 * 544;
    for (int c = t; c < 260; c += blockDim.x) {
      float s = 0.f;
      for (int p = 0; p < 49; p++) s += (float)base[p * 544 + c];
      objsel[blk * 260 + c] = s * (1.f / 245.f);
    }
  } else {
    if (t < 256) {
      float s = 0.f;
      const float* p = glob + t * 49;
      for (int q = 0; q < 49; q++) s += p[q];
      g[t] = s * (1.f / 49.f);
    }
  }
}

__global__ void fc1_kernel(const float* __restrict__ objsel,
                           const float* __restrict__ g,
                           const float* __restrict__ w,
                           const float* __restrict__ b,
                           float* __restrict__ x1) {
  const int co = threadIdx.x;
  float acc[5];
#pragma unroll
  for (int i = 0; i < 5; i++) acc[i] = b[co];
  for (int k = 0; k < 260; k++) {
    const float wv = w[k * 256 + co];
#pragma unroll
    for (int i = 0; i < 5; i++) acc[i] = fmaf(objsel[i * 260 + k], wv, acc[i]);
  }
  for (int k = 260; k < 516; k++) {
    const float wv = w[k * 256 + co];
    const float gv = g[k - 260];
#pragma unroll
    for (int i = 0; i < 5; i++) acc[i] = fmaf(gv, wv, acc[i]);
  }
#pragma unroll
  for (int i = 0; i < 5; i++) x1[i * 256 + co] = fmaxf(acc[i], 0.f);
}

__global__ void fc23_kernel(const float* __restrict__ x1,
                            const float* __restrict__ w2,
                            const float* __restrict__ b2,
                            const float* __restrict__ w3,
                            const float* __restrict__ b3,
                            float* __restrict__ out) {
  __shared__ float x2[64];
  const int j = threadIdx.x;
  float acc = b2[j];
  for (int k = 0; k < 1280; k++) acc = fmaf(x1[k], w2[k * 64 + j], acc);
  x2[j] = fmaxf(acc, 0.f);
  __syncthreads();
  if (j < 4) {
    float a = b3[j];
    for (int k = 0; k < 64; k++) a = fmaf(x2[k], w3[k * 4 + j], a);
    out[j] = a;
  }
}

// ---------------------------------------------------------------------------
extern "C" void kernel_launch(void* const* d_in, const int* in_sizes, int n_in,
                              void* d_out, int out_size, void* d_ws, size_t ws_size,
                              hipStream_t stream) {
  (void)in_sizes; (void)n_in; (void)out_size;
  const float* glob_feature = (const float*)d_in[0];
  const float* roi          = (const float*)d_in[1];
  const float* bbox         = (const float*)d_in[2];
  const float* w_glob1      = (const float*)d_in[3];
  const float* b_glob1      = (const float*)d_in[4];
  const float* w_glob2      = (const float*)d_in[5];
  const float* b_glob2      = (const float*)d_in[6];
  const float* w_obj1       = (const float*)d_in[7];
  const float* b_obj1       = (const float*)d_in[8];
  const float* w_obj2       = (const float*)d_in[9];
  const float* b_obj2       = (const float*)d_in[10];
  const float* w_sel1       = (const float*)d_in[11];
  const float* b_sel1       = (const float*)d_in[12];
  const float* w_sel2       = (const float*)d_in[13];
  const float* b_sel2       = (const float*)d_in[14];
  const float* w_sel3       = (const float*)d_in[15];
  const float* b_sel3       = (const float*)d_in[16];
  const float* w_fc1        = (const float*)d_in[17];
  const float* b_fc1        = (const float*)d_in[18];
  const float* w_fc2        = (const float*)d_in[19];
  const float* b_fc2        = (const float*)d_in[20];
  const float* w_fc3        = (const float*)d_in[21];
  const float* b_fc3        = (const float*)d_in[22];

  float* ws = (float*)d_ws;
  const bool big = ws_size >= (size_t)115000000;   // fast path needs 114.82 MB

  // common small-buffer pointers (set per path below)
  _Float16 *xh1, *wbuf1, *obj1buf, *sint, *wbuf2, *wbufs1;
  float *sel1buf, *glob1buf, *part1, *part2, *sel2buf, *globbuf, *objsel, *gbuf, *x1buf;
  int* idxbuf;

  if (big) {
    xh1      = (_Float16*)(ws);                    // 25,690,112 halves
    wbuf1    = (_Float16*)(ws + 12845056);         // 18,874,368 halves
    obj1buf  = (_Float16*)(ws + 22282240);         // 12,845,056 halves [obj][49][1024]
    // region [0, 12845056) reused after obj1:
    sint     = (_Float16*)(ws);                    // 6,823,936 halves [obj][49][544]
    wbuf2    = (_Float16*)(ws + 3411968);
    wbufs1   = (_Float16*)(ws + 4591616);
    sel1buf  = ws + 5218304;
    glob1buf = ws + 6856704;
    part1    = ws + 6957056;
    part2    = ws + 8562688;
    sel2buf  = ws + 8763392;
    globbuf  = ws + 8800256;
    idxbuf   = (int*)(ws + 8812800);
    objsel   = ws + 8812808;
    gbuf     = ws + 8814108;
    x1buf    = ws + 8814364;
  } else {
    xh1      = nullptr;
    wbuf1    = (_Float16*)(ws);                    // 18,874,368 halves
    sint     = (_Float16*)(ws);                    // alias (post-obj1)
    wbuf2    = (_Float16*)(ws + 3412000);
    wbufs1   = (_Float16*)(ws + 4591648);
    sel1buf  = ws + 5218336;
    glob1buf = ws + 6856736;
    part1    = ws + 6957088;
    part2    = ws + 8562720;
    sel2buf  = ws + 8763424;
    obj1buf  = (_Float16*)(ws + 9437184);          // [obj][49][1024]
    globbuf  = ws + 15859712;
    idxbuf   = (int*)(ws + 15872256);
    objsel   = ws + 15872264;
    gbuf     = ws + 15873564;
    x1buf    = ws + 15873820;
  }

  // --- obj1 ---
  transform_w<2048, 2048, 1024, 256><<<dim3(64, 32), 256, 0, stream>>>(w_obj1, wbuf1);
  if (big) {
    convert_tr<<<dim3(16, 256), 256, 0, stream>>>(roi, xh1);
    conv_mfma<2048, 1024, 256, 4, 7, 1, true, 2048, true, _Float16, _Float16>
        <<<dim3(4, 128), 512, 0, stream>>>(wbuf1, xh1, b_obj1, obj1buf, 1024, 0);
  } else {
    conv_mfma<2048, 1024, 256, 4, 7, 1, false, 0, true, _Float16, float>
        <<<dim3(4, 128), 512, 0, stream>>>(wbuf1, roi, b_obj1, obj1buf, 1024, 0);
  }

  // --- region A free now: transforms + glob path ---
  transform_w<1024, 1024, 256, 128><<<dim3(32, 8), 256, 0, stream>>>(w_obj2, wbuf2);
  transform_w<516, 544, 256, 128><<<dim3(17, 8), 256, 0, stream>>>(w_sel1, wbufs1);

  conv_gemm<512, 1024, 4, 4, 28, 28, 14, 14, 2, 1, 1, 512, 0, true, 4, 4, 16, true>
      <<<dim3(4, 8, 16), 256, 0, stream>>>(w_glob1, glob_feature, b_glob1, part1);
  reduce_bias_relu<<<dim3(392), 256, 0, stream>>>(part1, b_glob1, glob1buf, 100352, 196, 16);
  conv_gemm<256, 512, 4, 4, 14, 14, 7, 7, 2, 1, 1, 256, 0, true, 4, 4, 16, true>
      <<<dim3(1, 4, 16), 256, 0, stream>>>(w_glob2, glob1buf, b_glob2, part2);
  reduce_bias_relu<<<dim3(49), 256, 0, stream>>>(part2, b_glob2, globbuf, 12544, 49, 16);

  prep_sin_t<<<dim3(256), 256, 0, stream>>>(bbox, globbuf, sint);

  // --- obj2 (writes sin_t ch 4..259), sel branch ---
  conv_mfma<1024, 256, 128, 4, 7, 1, true, 1024, true, _Float16, _Float16>
      <<<dim3(2, 128), 512, 0, stream>>>(wbuf2, obj1buf, b_obj2, sint, 544, 4);
  conv_mfma<544, 256, 128, 2, 5, 0, true, 544, false, float, _Float16>
      <<<dim3(2, 128), 512, 0, stream>>>(wbufs1, sint, b_sel1, sel1buf, 256, 0);
  sel2_kernel<<<dim3(1024), 256, 0, stream>>>(sel1buf, w_sel2, b_sel2, sel2buf);
  score_top5<<<dim3(1), 256, 0, stream>>>(sel2buf, w_sel3, b_sel3, idxbuf);

  // --- pooling + FC head ---
  pool_t<<<dim3(6), 256, 0, stream>>>(sint, globbuf, idxbuf, objsel, gbuf);
  fc1_kernel<<<dim3(1), 256, 0, stream>>>(objsel, gbuf, w_fc1, b_fc1, x1buf);
  fc23_kernel<<<dim3(1), 64, 0, stream>>>(x1buf, w_fc2, b_fc2, w_fc3, b_fc3,
                                          (float*)d_out);
}

// Round 7
// 991.638 us; speedup vs baseline: 1.1640x; 1.1640x over previous
//
#include <hip/hip_runtime.h>
#include <math.h>

using half8 = __attribute__((ext_vector_type(8))) _Float16;
using half4 = __attribute__((ext_vector_type(4))) _Float16;
using f32x4 = __attribute__((ext_vector_type(4))) float;

// ---------------------------------------------------------------------------
// Weight re-tiling: w (OIHW fp32) -> Wt fp16 tiles [mt][ktile][g][mi][8].
// ktile order: cc (ci chunks of 128) -> khkw (9) -> sub (cw/32).
// Element (g,mi,i) of tile = w[mt*BM+mi][cc*128+sub*32+8g+i][khkw].
// ---------------------------------------------------------------------------
template<int CIN, int KC, int M_, int BM>
__global__ __launch_bounds__(256)
void transform_w(const float* __restrict__ w, _Float16* __restrict__ wt) {
  constexpr int NT = (KC / 32) * 9;
  __shared__ float lds[32 * 289];
  const int tid = threadIdx.x;
  const int s   = blockIdx.x;          // ci chunk of 32: ci0 = 32*s
  const int m0  = blockIdx.y * 32;
  const int ci0 = s * 32;
  int vlen = (CIN - ci0) * 9;          // valid floats per row chunk
  if (vlen > 288) vlen = 288;
  if (vlen < 0) vlen = 0;

  for (int e = tid; e < 32 * 288; e += 256) {
    const int mi = e / 288, o = e - mi * 288;
    float v = 0.f;
    if (o < vlen) v = w[(size_t)(m0 + mi) * (CIN * 9) + (size_t)ci0 * 9 + o];
    lds[mi * 289 + o] = v;
  }
  __syncthreads();

  const int cc  = s >> 2;
  const int sub = s & 3;
  int ns = (KC - 128 * cc) / 32; if (ns > 4) ns = 4;
  const int mt = m0 / BM;
  const int mb = m0 - mt * BM;
  _Float16* base = wt + (size_t)mt * NT * (BM * 32);

  for (int u = tid; u < 36 * 256; u += 256) {
    const int chunk  = u >> 8;
    const int within = u & 255;
    const int g = chunk & 3, khkw = chunk >> 2;
    const int mi = within >> 3, i = within & 7;
    const int kt = 36 * cc + khkw * ns + sub;
    const float v = lds[mi * 289 + (8 * g + i) * 9 + khkw];
    base[(size_t)kt * (BM * 32) + g * (BM * 8) + (mb + mi) * 8 + i] = (_Float16)v;
  }
}

// ---------------------------------------------------------------------------
// Convert + transpose roi: (256, 2048, 49) fp32 NCHW -> xh1[obj][pos][ci] fp16.
// ---------------------------------------------------------------------------
__global__ __launch_bounds__(256)
void convert_tr(const float* __restrict__ x, _Float16* __restrict__ xh) {
  __shared__ _Float16 t_s[49][136];
  const int tid   = threadIdx.x;
  const int cbase = blockIdx.x * 128;
  const int obj   = blockIdx.y;
  const float* src = x + (size_t)obj * 2048 * 49 + (size_t)cbase * 49;
  for (int e = tid; e < 128 * 49; e += 256) {
    const int ci = e / 49, pos = e - ci * 49;
    t_s[pos][ci] = (_Float16)src[e];
  }
  __syncthreads();
  _Float16* dst = xh + (size_t)obj * 49 * 2048 + cbase;
  for (int u = tid; u < 49 * 16; u += 256) {
    const int pos = u >> 4, l = u & 15;
    *(half8*)&dst[(size_t)pos * 2048 + l * 8] = *(const half8*)&t_s[pos][l * 8];
  }
}

// ---------------------------------------------------------------------------
// fp16 MFMA implicit-GEMM conv, 3x3 on 7x7 (or 5x5-out), NCHW-transposed IO.
// - X fp16 [obj][pos][KC]; staged per 128-ci chunk into x_s; staging loads for
//   chunk c+1 stay IN FLIGHT across the MFMA phase (raw s_barrier, lgkm-only
//   waits -- no vmcnt drain).
// - Weights: register pipeline depth 2 (3 rotating buffers afA/B/C, linear
//   global walk, rolling across chunk boundaries).
// - s_setprio(1) around each ktile's MFMA burst (waves are phase-diverse).
// - TOUT: epilogue LDS-transpose -> coalesced [pos][channel] half4 row writes.
// - XCD-aware block decode: XCD j owns one mt weight tile (L2 locality).
// ---------------------------------------------------------------------------
template<int KC, int BM, int FN, int OHW, int PAD, bool TOUT, typename OUT_T,
         int NMT, int NOP>
__global__ __launch_bounds__(512)
void conv_mfma(const _Float16* __restrict__ Wt, const _Float16* __restrict__ X,
               const float* __restrict__ bias, OUT_T* __restrict__ out,
               int outc, int co_off) {
  constexpr int NT    = (KC / 32) * 9;
  constexpr int OPOS  = OHW * OHW;
  constexpr int WM    = BM / 4;
  constexpr int FR    = WM / 16;
  constexpr int CFULL = KC / 128;
  constexpr int TAIL  = KC - CFULL * 128;          // 0 or 32
  constexpr int NCH   = CFULL + (TAIL ? 1 : 0);

  __shared__ alignas(16) _Float16 x_s[2][50][136];

  const int tid  = threadIdx.x;
  const int wid  = tid >> 6;
  const int lane = tid & 63;
  const int g    = lane >> 4;
  const int ln   = lane & 15;
  const int obj  = wid >> 2;
  const int wm   = (wid & 3) * WM;

  // XCD-aware decode: dispatch round-robins blockIdx%8 across XCDs.
  const int bid = blockIdx.x;
  const int j = bid & 7, q = bid >> 3;
  constexpr int OPJ = 8 / NMT;
  const int mt = j / OPJ;
  const int op = (j % OPJ) * (NOP / OPJ) + q;

  if (tid < 272) x_s[tid / 136][49][tid % 136] = (_Float16)0.f;

  int ohv[FN], owv[FN];
  bool pvv[FN];
#pragma unroll
  for (int f = 0; f < FN; f++) {
    const int pos = ln + 16 * f;
    pvv[f] = pos < OPOS;
    ohv[f] = pos / OHW;
    owv[f] = pos % OHW;
  }

  f32x4 acc[FR][FN];
#pragma unroll
  for (int r = 0; r < FR; r++)
#pragma unroll
    for (int f = 0; f < FN; f++) acc[r][f] = (f32x4){0.f, 0.f, 0.f, 0.f};

  const _Float16* Xh = X + (size_t)(2 * op) * 49 * KC;

  half8 rg[4];
  auto load_chunk = [&](int cbase, int cw) {
    if (cw == 128) {
#pragma unroll
      for (int v = 0; v < 4; v++) {
        const int u = v * 512 + tid;
        if (u < 1568) {
          const int row = u >> 4, l = u & 15;
          const int o = row >= 49 ? 1 : 0, pos = row - 49 * o;
          rg[v] = *(const half8*)(Xh + (size_t)(o * 49 + pos) * KC + cbase + l * 8);
        }
      }
    } else {  // cw == 32
      if (tid < 392) {
        const int row = tid >> 2, l = tid & 3;
        const int o = row >= 49 ? 1 : 0, pos = row - 49 * o;
        rg[0] = *(const half8*)(Xh + (size_t)(o * 49 + pos) * KC + cbase + l * 8);
      }
    }
  };
  auto write_chunk = [&](int cw) {
    if (cw == 128) {
#pragma unroll
      for (int v = 0; v < 4; v++) {
        const int u = v * 512 + tid;
        if (u < 1568) {
          const int row = u >> 4, l = u & 15;
          const int o = row >= 49 ? 1 : 0, pos = row - 49 * o;
          *(half8*)&x_s[o][pos][l * 8] = rg[v];
        }
      }
    } else {
      if (tid < 392) {
        const int row = tid >> 2, l = tid & 3;
        const int o = row >= 49 ? 1 : 0, pos = row - 49 * o;
        *(half8*)&x_s[o][pos][l * 8] = rg[0];
      }
    }
  };

  // --- weight pipeline: depth 2, 3 named buffers, linear walk over ktiles ---
  const int afoff = (g * BM + wm + ln) * 8;
  const _Float16* ap = Wt + (size_t)mt * NT * (BM * 32) + afoff;
  half8 afA[FR], afB[FR], afC[FR];
#pragma unroll
  for (int r = 0; r < FR; r++) afA[r] = *(const half8*)(ap + r * 128);
  ap += BM * 32;
#pragma unroll
  for (int r = 0; r < FR; r++) afB[r] = *(const half8*)(ap + r * 128);
  ap += BM * 32;
  // (last 2 prefetches read <=32KB past this mt tile -- valid ws memory,
  //  values never consumed)

  load_chunk(0, KC < 128 ? KC : 128);

  auto kstep = [&](half8 (&cur)[FR], half8 (&fut)[FR], int subbyte,
                   const int (&boff)[FN]) {
#pragma unroll
    for (int r = 0; r < FR; r++) fut[r] = *(const half8*)(ap + r * 128);
    ap += BM * 32;
    __builtin_amdgcn_s_setprio(1);
    const char* xb = (const char*)(&x_s[0][0][0]) + subbyte;
#pragma unroll
    for (int f = 0; f < FN; f++) {
      const half8 bf = *(const half8*)(xb + boff[f]);
#pragma unroll
      for (int r = 0; r < FR; r++)
        acc[r][f] = __builtin_amdgcn_mfma_f32_16x16x32_f16(cur[r], bf, acc[r][f], 0, 0, 0);
    }
    __builtin_amdgcn_s_setprio(0);
  };

  for (int c = 0; c < NCH; c++) {
    const int cw = (c < CFULL) ? 128 : TAIL;
    // barrier A: all waves done reading x_s chunk c-1 (their ds_reads were
    // consumed by MFMAs already -> no waitcnt needed). Raw barrier: does NOT
    // drain vmcnt, so rg/af loads stay in flight.
    asm volatile("s_barrier" ::: "memory");
    write_chunk(cw);                       // rg -> LDS (vmcnt wait is implicit)
    if (c + 1 < NCH)
      load_chunk((c + 1) * 128, (c + 1 < CFULL) ? 128 : TAIL);  // in flight
    // barrier B: my ds_writes drained (lgkm only), then sync. No vmcnt drain.
    asm volatile("s_waitcnt lgkmcnt(0)\n\ts_barrier" ::: "memory");

    if (cw == 128) {
#pragma unroll
      for (int t9 = 0; t9 < 9; t9++) {
        const int kh = t9 / 3, kw = t9 - 3 * (t9 / 3);
        int boff[FN];
#pragma unroll
        for (int f = 0; f < FN; f++) {
          const int ih = ohv[f] + kh - PAD;
          const int iw = owv[f] + kw - PAD;
          bool v = pvv[f];
          if (PAD) v = v && ((unsigned)ih < 7u) && ((unsigned)iw < 7u);
          const int row = v ? (ih * 7 + iw) : 49;
          boff[f] = (obj * 50 * 136 + row * 136) * 2;
        }
#pragma unroll
        for (int s4 = 0; s4 < 4; s4++) {
          const int ph = (t9 * 4 + s4) % 3;      // constant after unroll
          const int subbyte = (s4 * 32 + 8 * g) * 2;
          if (ph == 0)      kstep(afA, afC, subbyte, boff);
          else if (ph == 1) kstep(afB, afA, subbyte, boff);
          else              kstep(afC, afB, subbyte, boff);
        }
      }
    } else {  // tail chunk: cw==32, nsub==1, 9 ktiles
#pragma unroll
      for (int t9 = 0; t9 < 9; t9++) {
        const int kh = t9 / 3, kw = t9 - 3 * (t9 / 3);
        int boff[FN];
#pragma unroll
        for (int f = 0; f < FN; f++) {
          const int ih = ohv[f] + kh - PAD;
          const int iw = owv[f] + kw - PAD;
          bool v = pvv[f];
          if (PAD) v = v && ((unsigned)ih < 7u) && ((unsigned)iw < 7u);
          const int row = v ? (ih * 7 + iw) : 49;
          boff[f] = (obj * 50 * 136 + row * 136) * 2;
        }
        const int ph = t9 % 3;
        const int subbyte = (8 * g) * 2;
        if (ph == 0)      kstep(afA, afC, subbyte, boff);
        else if (ph == 1) kstep(afB, afA, subbyte, boff);
        else              kstep(afC, afB, subbyte, boff);
      }
    }
  }

  // ---- epilogue ----
  if constexpr (TOUT) {
    // LDS transpose -> coalesced [pos][channel] writes (half4, 8B-aligned for
    // any co_off%4==0). PASSES = BM/128 channel halves.
    __shared__ alignas(16) _Float16 ot_s[2][49][132];
    constexpr int PASSES = BM / 128;
#pragma unroll
    for (int p = 0; p < PASSES; p++) {
      if (p) asm volatile("s_barrier" ::: "memory");   // protect prev pass read
      if (wm >= 128 * p && wm < 128 * (p + 1)) {
#pragma unroll
        for (int f = 0; f < FN; f++) {
          const int pos = ln + 16 * f;
          if (pos < OPOS) {
#pragma unroll
            for (int r = 0; r < FR; r++) {
              const int cl = wm - 128 * p + r * 16 + g * 4;
              half4 h;
#pragma unroll
              for (int e = 0; e < 4; e++)
                h[e] = (_Float16)fmaxf(
                    acc[r][f][e] + bias[mt * BM + wm + r * 16 + g * 4 + e], 0.f);
              *(half4*)&ot_s[obj][pos][cl] = h;
            }
          }
        }
      }
      asm volatile("s_waitcnt lgkmcnt(0)\n\ts_barrier" ::: "memory");
      _Float16* dst = (_Float16*)out;
      for (int u = tid; u < 2 * 49 * 32; u += 512) {
        const int row = u >> 5, l = u & 31;
        const int o = row >= 49 ? 1 : 0, pos = row - 49 * o;
        const half4 v = *(const half4*)&ot_s[o][pos][l * 4];
        *(half4*)&dst[((size_t)(2 * op + o) * OPOS + pos) * outc +
                      co_off + mt * BM + 128 * p + l * 4] = v;
      }
    }
  } else {
    const int bo = 2 * op + obj;
#pragma unroll
    for (int f = 0; f < FN; f++) {
      const int pos = ln + 16 * f;
      if (pos < OPOS) {
#pragma unroll
        for (int r = 0; r < FR; r++) {
          const int mrow = mt * BM + wm + r * 16 + g * 4;
#pragma unroll
          for (int e = 0; e < 4; e++) {
            const int m = mrow + e;
            float v = fmaxf(acc[r][f][e] + bias[m], 0.f);
            out[((size_t)bo * outc + co_off + m) * OPOS + pos] = (OUT_T)v;
          }
        }
      }
    }
  }
}

// ---------------------------------------------------------------------------
// fp32 implicit-GEMM conv + optional split-K partial output (glob path).
// ---------------------------------------------------------------------------
template<int M_, int CIN, int KH, int KW, int H, int W, int OH, int OW,
         int STRIDE, int PAD, int BATCH, int OUTC, int CO_OFF, bool RELU,
         int TM, int TN, int KSPLIT, bool PARTIAL>
__global__ __launch_bounds__(256)
void conv_gemm(const float* __restrict__ A,
               const float* __restrict__ X,
               const float* __restrict__ bias,
               float* __restrict__ out) {
  constexpr int K   = CIN * KH * KW;
  constexpr int N   = BATCH * OH * OW;
  constexpr int BK  = 16;
  constexpr int BM  = 16 * TM;
  constexpr int BN  = 16 * TN;
  constexpr int KCH = K / KSPLIT;

  __shared__ float a_s[BK][BM];
  __shared__ float b_s[BK][BN];

  const int t  = threadIdx.x;
  const int tx = t & 15;
  const int ty = t >> 4;
  const int n0 = blockIdx.x * BN;
  const int m0 = blockIdx.y * BM;
  const int kz = blockIdx.z;

  constexpr int AQ    = TM / 4;
  constexpr int TPR_A = 4 / AQ;
  const int am = t / TPR_A;
  const int ak = (t % TPR_A) * (4 * AQ);

  constexpr int BQ = TN / 4;
  const int bk = t & 15;
  const int bn = (t >> 4) * TN;

  float acc[TM][TN];
#pragma unroll
  for (int i = 0; i < TM; i++)
#pragma unroll
    for (int j = 0; j < TN; j++) acc[i][j] = 0.f;

  for (int k0 = kz * KCH; k0 < (kz + 1) * KCH; k0 += BK) {
    float4 av[AQ];
#pragma unroll
    for (int q = 0; q < AQ; q++) {
      av[q] = make_float4(0.f, 0.f, 0.f, 0.f);
      const int kq = k0 + ak + 4 * q;
      if ((m0 + am) < M_ && kq < K)
        av[q] = *reinterpret_cast<const float4*>(&A[(m0 + am) * K + kq]);
    }
    float bv[TN];
#pragma unroll
    for (int q = 0; q < TN; q++) bv[q] = 0.f;
    {
      const int kk = k0 + bk;
      if (kk < K) {
        const int ci = kk / (KH * KW);
        const int r  = kk - ci * (KH * KW);
        const int kh = r / KW;
        const int kw = r - kh * KW;
#pragma unroll
        for (int q = 0; q < TN; q++) {
          const int n = n0 + bn + q;
          if (n < N) {
            const int b   = n / (OH * OW);
            const int pos = n - b * (OH * OW);
            const int oh  = pos / OW;
            const int ow  = pos - oh * OW;
            const int ih  = oh * STRIDE - PAD + kh;
            const int iw  = ow * STRIDE - PAD + kw;
            if (ih >= 0 && ih < H && iw >= 0 && iw < W)
              bv[q] = X[((b * CIN + ci) * H + ih) * W + iw];
          }
        }
      }
    }
    __syncthreads();
#pragma unroll
    for (int q = 0; q < AQ; q++) {
      const int kq = ak + 4 * q;
      a_s[kq + 0][am] = av[q].x;
      a_s[kq + 1][am] = av[q].y;
      a_s[kq + 2][am] = av[q].z;
      a_s[kq + 3][am] = av[q].w;
    }
#pragma unroll
    for (int q = 0; q < BQ; q++)
      *reinterpret_cast<float4*>(&b_s[bk][bn + 4 * q]) =
          make_float4(bv[4 * q], bv[4 * q + 1], bv[4 * q + 2], bv[4 * q + 3]);
    __syncthreads();
#pragma unroll
    for (int kk2 = 0; kk2 < BK; kk2++) {
      float a[TM], b[TN];
#pragma unroll
      for (int q = 0; q < AQ; q++)
        *reinterpret_cast<float4*>(&a[4 * q]) =
            *reinterpret_cast<const float4*>(&a_s[kk2][ty * TM + 4 * q]);
#pragma unroll
      for (int q = 0; q < BQ; q++)
        *reinterpret_cast<float4*>(&b[4 * q]) =
            *reinterpret_cast<const float4*>(&b_s[kk2][tx * TN + 4 * q]);
#pragma unroll
      for (int i = 0; i < TM; i++)
#pragma unroll
        for (int j = 0; j < TN; j++)
          acc[i][j] = fmaf(a[i], b[j], acc[i][j]);
    }
  }

#pragma unroll
  for (int i = 0; i < TM; i++) {
    const int m = m0 + ty * TM + i;
    if (m < M_) {
#pragma unroll
      for (int j = 0; j < TN; j++) {
        const int n = n0 + tx * TN + j;
        if (n < N) {
          if (PARTIAL) {
            out[((size_t)kz * M_ + m) * N + n] = acc[i][j];
          } else {
            float v = acc[i][j] + bias[m];
            if (RELU) v = fmaxf(v, 0.f);
            const int b   = n / (OH * OW);
            const int pos = n - b * (OH * OW);
            out[(b * OUTC + CO_OFF + m) * (OH * OW) + pos] = v;
          }
        }
      }
    }
  }
}

__global__ void reduce_bias_relu(const float* __restrict__ part,
                                 const float* __restrict__ bias,
                                 float* __restrict__ out, int MN, int N, int KS) {
  const int e = blockIdx.x * 256 + threadIdx.x;
  if (e >= MN) return;
  float s = 0.f;
  for (int k = 0; k < KS; k++) s += part[(size_t)k * MN + e];
  s += bias[e / N];
  out[e] = fmaxf(s, 0.f);
}

// ---------------------------------------------------------------------------
// sel2: x = sel1buf f32 (256,256,5,5) NCHW, w (16,256,3,3) -> out (256,16,9).
// ---------------------------------------------------------------------------
__global__ __launch_bounds__(256)
void sel2_kernel(const float* __restrict__ x, const float* __restrict__ w,
                 const float* __restrict__ b, float* __restrict__ out) {
  const int wv   = (blockIdx.x * 256 + threadIdx.x) >> 6;
  const int lane = threadIdx.x & 63;
  const int obj  = wv >> 4, co = wv & 15;
  float acc[9];
#pragma unroll
  for (int p = 0; p < 9; p++) acc[p] = 0.f;
  const float* xo = x + (size_t)obj * 256 * 25;
  const float* wo = w + (size_t)co * 2304;
  for (int k = lane; k < 2304; k += 64) {
    const int ci = k / 9, rr = k - 9 * ci;
    const int kh = rr / 3, kw = rr - 3 * kh;
    const float wval = wo[k];
    const float* xc = xo + ci * 25;
#pragma unroll
    for (int oh = 0; oh < 3; oh++)
#pragma unroll
      for (int ow = 0; ow < 3; ow++)
        acc[oh * 3 + ow] = fmaf(xc[(oh + kh) * 5 + (ow + kw)], wval, acc[oh * 3 + ow]);
  }
  const float bv = b[co];
#pragma unroll
  for (int p = 0; p < 9; p++) {
    float v = acc[p];
#pragma unroll
    for (int off = 32; off; off >>= 1) v += __shfl_xor(v, off);
    if (lane == 0) out[(size_t)wv * 9 + p] = fmaxf(v + bv, 0.f);
  }
}

// ---------------------------------------------------------------------------
// sin_t buffer (256, 49, 544) fp16: ch 0..3 = bb, 260..515 = glob, 516..543=0.
// (ch 4..259 written by obj2 conv's TOUT epilogue.)
// ---------------------------------------------------------------------------
__global__ void prep_sin_t(const float* __restrict__ bbox,
                           const float* __restrict__ glob,
                           _Float16* __restrict__ sint) {
  const int b = blockIdx.x;
  const float x0 = bbox[b * 4 + 0], y0 = bbox[b * 4 + 1];
  const float x1 = bbox[b * 4 + 2], y1 = bbox[b * 4 + 3];
  const float bbv[4] = {x0 / 1280.f, y0 / 720.f,
                        logf(1280.f / (x1 - x0)), logf(720.f / (y1 - y0))};
  _Float16* base = sint + (size_t)b * 49 * 544;
  for (int e = threadIdx.x; e < 49 * 288; e += blockDim.x) {
    const int pos = e / 288, q = e - pos * 288;
    float v; int c;
    if (q < 4)        { v = bbv[q];                  c = q; }
    else if (q < 260) { v = glob[(q - 4) * 49 + pos]; c = q + 256; }
    else              { v = 0.f;                      c = q + 256; }
    base[pos * 544 + c] = (_Float16)v;
  }
}

__global__ void score_top5(const float* __restrict__ sel2,
                           const float* __restrict__ w3,
                           const float* __restrict__ b3,
                           int* __restrict__ idx_out) {
  __shared__ float w_s[144];
  __shared__ float s_s[256];
  const int t = threadIdx.x;
  if (t < 144) w_s[t] = w3[t];
  __syncthreads();
  float acc = b3[0];
  const float* p = sel2 + t * 144;
  for (int k = 0; k < 144; k++) acc += p[k] * w_s[k];
  s_s[t] = acc;
  __syncthreads();
  if (t == 0) {
    for (int i = 0; i < 5; i++) {
      float best = -1e30f;
      int bi = 0;
      for (int j = 0; j < 256; j++)
        if (s_s[j] > best) { best = s_s[j]; bi = j; }
      idx_out[i] = bi;
      s_s[bi] = -1e30f;
    }
  }
}

__global__ void pool_t(const _Float16* __restrict__ sint,
                       const float* __restrict__ glob,
                       const int* __restrict__ idx,
                       float* __restrict__ objsel,
                       float* __restrict__ g) {
  const int blk = blockIdx.x;
  const int t = threadIdx.x;
  if (blk < 5) {
    const int b = idx[blk];
    const _Float16* base = sint + (size_t)b * 49 * 544;
    for (int c = t; c < 260; c += blockDim.x) {
      float s = 0.f;
      for (int p = 0; p < 49; p++) s += (float)base[p * 544 + c];
      objsel[blk * 260 + c] = s * (1.f / 245.f);
    }
  } else {
    if (t < 256) {
      float s = 0.f;
      const float* p = glob + t * 49;
      for (int q = 0; q < 49; q++) s += p[q];
      g[t] = s * (1.f / 49.f);
    }
  }
}

__global__ void fc1_kernel(const float* __restrict__ objsel,
                           const float* __restrict__ g,
                           const float* __restrict__ w,
                           const float* __restrict__ b,
                           float* __restrict__ x1) {
  const int co = threadIdx.x;
  float acc[5];
#pragma unroll
  for (int i = 0; i < 5; i++) acc[i] = b[co];
  for (int k = 0; k < 260; k++) {
    const float wv = w[k * 256 + co];
#pragma unroll
    for (int i = 0; i < 5; i++) acc[i] = fmaf(objsel[i * 260 + k], wv, acc[i]);
  }
  for (int k = 260; k < 516; k++) {
    const float wv = w[k * 256 + co];
    const float gv = g[k - 260];
#pragma unroll
    for (int i = 0; i < 5; i++) acc[i] = fmaf(gv, wv, acc[i]);
  }
#pragma unroll
  for (int i = 0; i < 5; i++) x1[i * 256 + co] = fmaxf(acc[i], 0.f);
}

__global__ void fc23_kernel(const float* __restrict__ x1,
                            const float* __restrict__ w2,
                            const float* __restrict__ b2,
                            const float* __restrict__ w3,
                            const float* __restrict__ b3,
                            float* __restrict__ out) {
  __shared__ float x2[64];
  const int j = threadIdx.x;
  float acc = b2[j];
  for (int k = 0; k < 1280; k++) acc = fmaf(x1[k], w2[k * 64 + j], acc);
  x2[j] = fmaxf(acc, 0.f);
  __syncthreads();
  if (j < 4) {
    float a = b3[j];
    for (int k = 0; k < 64; k++) a = fmaf(x2[k], w3[k * 4 + j], a);
    out[j] = a;
  }
}

// ---------------------------------------------------------------------------
extern "C" void kernel_launch(void* const* d_in, const int* in_sizes, int n_in,
                              void* d_out, int out_size, void* d_ws, size_t ws_size,
                              hipStream_t stream) {
  (void)in_sizes; (void)n_in; (void)out_size; (void)ws_size;
  const float* glob_feature = (const float*)d_in[0];
  const float* roi          = (const float*)d_in[1];
  const float* bbox         = (const float*)d_in[2];
  const float* w_glob1      = (const float*)d_in[3];
  const float* b_glob1      = (const float*)d_in[4];
  const float* w_glob2      = (const float*)d_in[5];
  const float* b_glob2      = (const float*)d_in[6];
  const float* w_obj1       = (const float*)d_in[7];
  const float* b_obj1       = (const float*)d_in[8];
  const float* w_obj2       = (const float*)d_in[9];
  const float* b_obj2       = (const float*)d_in[10];
  const float* w_sel1       = (const float*)d_in[11];
  const float* b_sel1       = (const float*)d_in[12];
  const float* w_sel2       = (const float*)d_in[13];
  const float* b_sel2       = (const float*)d_in[14];
  const float* w_sel3       = (const float*)d_in[15];
  const float* b_sel3       = (const float*)d_in[16];
  const float* w_fc1        = (const float*)d_in[17];
  const float* b_fc1        = (const float*)d_in[18];
  const float* w_fc2        = (const float*)d_in[19];
  const float* b_fc2        = (const float*)d_in[20];
  const float* w_fc3        = (const float*)d_in[21];
  const float* b_fc3        = (const float*)d_in[22];

  float* ws = (float*)d_ws;
  _Float16* xh1     = (_Float16*)(ws);                 // 25,690,112 halves
  _Float16* wbuf1   = (_Float16*)(ws + 12845056);      // 18,874,368 halves
  _Float16* obj1buf = (_Float16*)(ws + 22282240);      // [obj][49][1024] fp16
  // region [0, 12845056) f32 reused after obj1:
  _Float16* sint    = (_Float16*)(ws);                 // [obj][49][544] fp16
  _Float16* wbuf2   = (_Float16*)(ws + 3411968);
  _Float16* wbufs1  = (_Float16*)(ws + 4591616);
  float*    sel1buf = ws + 5218304;
  float*    glob1buf= ws + 6856704;
  float*    part1   = ws + 6957056;
  float*    part2   = ws + 8562688;
  float*    sel2buf = ws + 8763392;
  float*    globbuf = ws + 8800256;
  int*      idxbuf  = (int*)(ws + 8812800);
  float*    objsel  = ws + 8812808;
  float*    gbuf    = ws + 8814108;
  float*    x1buf   = ws + 8814364;

  // --- obj1 ---
  transform_w<2048, 2048, 1024, 256><<<dim3(64, 32), 256, 0, stream>>>(w_obj1, wbuf1);
  convert_tr<<<dim3(16, 256), 256, 0, stream>>>(roi, xh1);
  conv_mfma<2048, 256, 4, 7, 1, true, _Float16, 4, 128>
      <<<dim3(512), 512, 0, stream>>>(wbuf1, xh1, b_obj1, obj1buf, 1024, 0);

  // --- region A free now: transforms + glob path ---
  transform_w<1024, 1024, 256, 128><<<dim3(32, 8), 256, 0, stream>>>(w_obj2, wbuf2);
  transform_w<516, 544, 256, 128><<<dim3(17, 8), 256, 0, stream>>>(w_sel1, wbufs1);

  conv_gemm<512, 1024, 4, 4, 28, 28, 14, 14, 2, 1, 1, 512, 0, true, 4, 4, 16, true>
      <<<dim3(4, 8, 16), 256, 0, stream>>>(w_glob1, glob_feature, b_glob1, part1);
  reduce_bias_relu<<<dim3(392), 256, 0, stream>>>(part1, b_glob1, glob1buf, 100352, 196, 16);
  conv_gemm<256, 512, 4, 4, 14, 14, 7, 7, 2, 1, 1, 256, 0, true, 4, 4, 16, true>
      <<<dim3(1, 4, 16), 256, 0, stream>>>(w_glob2, glob1buf, b_glob2, part2);
  reduce_bias_relu<<<dim3(49), 256, 0, stream>>>(part2, b_glob2, globbuf, 12544, 49, 16);

  prep_sin_t<<<dim3(256), 256, 0, stream>>>(bbox, globbuf, sint);

  // --- obj2 (writes sin_t ch 4..259), sel branch ---
  conv_mfma<1024, 128, 4, 7, 1, true, _Float16, 2, 128>
      <<<dim3(256), 512, 0, stream>>>(wbuf2, obj1buf, b_obj2, sint, 544, 4);
  conv_mfma<544, 128, 2, 5, 0, false, float, 2, 128>
      <<<dim3(256), 512, 0, stream>>>(wbufs1, sint, b_sel1, sel1buf, 256, 0);
  sel2_kernel<<<dim3(1024), 256, 0, stream>>>(sel1buf, w_sel2, b_sel2, sel2buf);
  score_top5<<<dim3(1), 256, 0, stream>>>(sel2buf, w_sel3, b_sel3, idxbuf);

  // --- pooling + FC head ---
  pool_t<<<dim3(6), 256, 0, stream>>>(sint, globbuf, idxbuf, objsel, gbuf);
  fc1_kernel<<<dim3(1), 256, 0, stream>>>(objsel, gbuf, w_fc1, b_fc1, x1buf);
  fc23_kernel<<<dim3(1), 64, 0, stream>>>(x1buf, w_fc2, b_fc2, w_fc3, b_fc3,
                                          (float*)d_out);
}